// Round 3
// baseline (278.708 us; speedup 1.0000x reference)
//
#include <hip/hip_runtime.h>

#define NBINS  20
#define BLOCKS 2048
#define TPB    256
#define PACK   256.0f   // A = 256*cnt + sse ; per-thread cnt<=32, sse<32 -> exact decode

__global__ __launch_bounds__(TPB, 8)
void dwmse_fused(const float* __restrict__ pred, const float* __restrict__ targ,
                 float* __restrict__ ws, float* __restrict__ out, int n, float inv_n)
{
    // h[b*TPB + tid]: per-thread private accumulator. bank = tid%32 -> conflict-free.
    __shared__ float h[NBINS * TPB];     // 20 KB -> 8 blocks/CU
    __shared__ int   last_flag;
    const int tid = threadIdx.x;

    #pragma unroll
    for (int b = 0; b < NBINS; ++b) h[b * TPB + tid] = 0.0f;
    __syncthreads();

    const int n4 = n >> 2;
    const float4* p4 = reinterpret_cast<const float4*>(pred);
    const float4* t4 = reinterpret_cast<const float4*>(targ);
    const int idx0 = blockIdx.x * TPB + tid;
    const int g    = gridDim.x * TPB;

    // ---- depth-3 software pipeline: two load-pairs always in flight ----
    float4 pa, ta, pb, tb;
    bool hasA = idx0 < n4;
    if (hasA) { pa = p4[idx0]; ta = t4[idx0]; }
    int ib = idx0 + g;
    bool hasB = ib < n4;
    if (hasB) { pb = p4[ib]; tb = t4[ib]; }

    while (hasA) {
        const int ic = ib + g;
        const bool hasC = ic < n4;
        float4 pc, tc;
        if (hasC) { pc = p4[ic]; tc = t4[ic]; }   // prefetch 2 ahead

        {   float d = pa.x - ta.x; float a = fmaf(d, d, PACK);
            int b = min(max((int)(ta.x * 20.0f), 0), NBINS - 1);
            h[b * TPB + tid] += a; }
        {   float d = pa.y - ta.y; float a = fmaf(d, d, PACK);
            int b = min(max((int)(ta.y * 20.0f), 0), NBINS - 1);
            h[b * TPB + tid] += a; }
        {   float d = pa.z - ta.z; float a = fmaf(d, d, PACK);
            int b = min(max((int)(ta.z * 20.0f), 0), NBINS - 1);
            h[b * TPB + tid] += a; }
        {   float d = pa.w - ta.w; float a = fmaf(d, d, PACK);
            int b = min(max((int)(ta.w * 20.0f), 0), NBINS - 1);
            h[b * TPB + tid] += a; }

        pa = pb; ta = tb; hasA = hasB;
        pb = pc; tb = tc; hasB = hasC;
        ib = ic;
    }
    // scalar tail (empty for N = 2^24)
    for (int k = (n4 << 2) + idx0; k < n; k += g) {
        float t = targ[k];
        float d = pred[k] - t; float a = fmaf(d, d, PACK);
        int b = min(max((int)(t * 20.0f), 0), NBINS - 1);
        h[b * TPB + tid] += a;
    }

    __syncthreads();

    // ---- block epilogue: decode, butterfly per wave, combine waves ----
    const int lane = tid & 63;
    const int wv   = tid >> 6;               // 4 waves
    float my_sse = 0.0f, my_cnt = 0.0f;

    for (int b = 0; b < NBINS; ++b) {
        float A = h[b * TPB + tid];
        float c = floorf(A * (1.0f / 256.0f));   // exact: sse < 256
        float s = A - 256.0f * c;
        #pragma unroll
        for (int m = 32; m; m >>= 1) { c += __shfl_xor(c, m); s += __shfl_xor(s, m); }
        if (lane == b) { my_cnt = c; my_sse = s; }
    }
    __syncthreads();                          // done reading h -> safe to reuse
    if (lane < NBINS) {
        h[wv * 2 * NBINS + lane]         = my_sse;
        h[wv * 2 * NBINS + NBINS + lane] = my_cnt;
    }
    __syncthreads();
    if (tid < NBINS) {
        float ss = 0.0f, cc = 0.0f;
        #pragma unroll
        for (int w = 0; w < TPB / 64; ++w) {
            ss += h[w * 2 * NBINS + tid];
            cc += h[w * 2 * NBINS + NBINS + tid];
        }
        unsafeAtomicAdd(&ws[tid], ss);            // single shared set: 2048 adds/address,
        unsafeAtomicAdd(&ws[NBINS + tid], cc);    // pipelined in L2 -> cheap
    }

    // ---- last-block finalization (replaces pass2 kernel) ----
    __threadfence();                              // release partials
    if (tid == 0) {
        int old = atomicAdd(reinterpret_cast<int*>(ws + 2 * NBINS), 1);
        last_flag = (old == (int)gridDim.x - 1);
    }
    __syncthreads();
    if (last_flag != 0 && tid < 64) {
        // coherent read of partials via atomic fetch-add(0)
        float col = 0.0f;
        if (tid < 2 * NBINS) col = atomicAdd(&ws[tid], 0.0f);

        float sse = col;
        float cnt = __shfl(col, tid + 20);        // lanes 0..19 get counts

        float w = 0.0f;
        if (tid < NBINS) {
            float c = fmaxf(cnt, 1.0f);
            w = __powf(c, -0.9f);
        }
        float s = w;
        #pragma unroll
        for (int off = 32; off > 0; off >>= 1) s += __shfl_down(s, off);
        s = __shfl(s, 0);

        float wb = (s > 0.0f) ? (w * (20.0f / s)) : w;
        wb = fmaxf(wb, 1.0f);

        float contrib = (tid < NBINS) ? (wb * sse) : 0.0f;
        #pragma unroll
        for (int off = 32; off > 0; off >>= 1) contrib += __shfl_down(contrib, off);

        if (tid == 0) out[0] = contrib * inv_n;
    }
}

extern "C" void kernel_launch(void* const* d_in, const int* in_sizes, int n_in,
                              void* d_out, int out_size, void* d_ws, size_t ws_size,
                              hipStream_t stream)
{
    const float* pred = (const float*)d_in[0];
    const float* targ = (const float*)d_in[1];
    float*       out  = (float*)d_out;
    float*       ws   = (float*)d_ws;
    const int n = in_sizes[0];

    // zero: 40 partial floats + 1 int done-counter = 164 bytes
    hipMemsetAsync(d_ws, 0, (2 * NBINS) * sizeof(float) + sizeof(int), stream);
    dwmse_fused<<<BLOCKS, TPB, 0, stream>>>(pred, targ, ws, out, n, 1.0f / (float)n);
}

// Round 4
// 221.919 us; speedup vs baseline: 1.2559x; 1.2559x over previous
//
#include <hip/hip_runtime.h>

#define NBINS  20
#define NSETS  32          // replicated global accumulator slots (power of 2)
#define BLOCKS 2048
#define TPB    256
#define PACK   256.0f      // A = 256*cnt + sse ; per-thread cnt<=32, sse<32 -> exact decode

// ---------------- Pass 1: per-bin packed (count,sse) histogram ----------------
__global__ __launch_bounds__(TPB, 8)
void dwmse_pass1(const float* __restrict__ pred, const float* __restrict__ targ,
                 float* __restrict__ ws, int n, int setMask)
{
    // h[b*TPB + tid]: lane-private slot. bank = tid%32 -> conflict-free, no collisions.
    // ds_add_f32 (unsafeAtomicAdd, result unused) -> NO read-back, NO lgkmcnt chain.
    __shared__ float h[NBINS * TPB];     // 20 KB -> 8 blocks/CU
    const int tid = threadIdx.x;

    #pragma unroll
    for (int b = 0; b < NBINS; ++b) h[b * TPB + tid] = 0.0f;
    __syncthreads();

    const int n4 = n >> 2;
    const float4* p4 = reinterpret_cast<const float4*>(pred);
    const float4* t4 = reinterpret_cast<const float4*>(targ);
    const int idx0    = blockIdx.x * TPB + tid;
    const int gstride = gridDim.x * TPB;

    int i = idx0;
    if (i < n4) {
        float4 p = p4[i];
        float4 t = t4[i];
        for (;;) {
            const int j = i + gstride;
            const bool more = (j < n4);
            float4 pn, tn;
            if (more) { pn = p4[j]; tn = t4[j]; }   // prefetch next iteration

            {   float d = p.x - t.x; float a = fmaf(d, d, PACK);
                int b = min(max((int)(t.x * 20.0f), 0), NBINS - 1);
                unsafeAtomicAdd(&h[b * TPB + tid], a); }
            {   float d = p.y - t.y; float a = fmaf(d, d, PACK);
                int b = min(max((int)(t.y * 20.0f), 0), NBINS - 1);
                unsafeAtomicAdd(&h[b * TPB + tid], a); }
            {   float d = p.z - t.z; float a = fmaf(d, d, PACK);
                int b = min(max((int)(t.z * 20.0f), 0), NBINS - 1);
                unsafeAtomicAdd(&h[b * TPB + tid], a); }
            {   float d = p.w - t.w; float a = fmaf(d, d, PACK);
                int b = min(max((int)(t.w * 20.0f), 0), NBINS - 1);
                unsafeAtomicAdd(&h[b * TPB + tid], a); }

            if (!more) break;
            p = pn; t = tn; i = j;
        }
    }
    // scalar tail (empty for N = 2^24)
    for (int k = (n4 << 2) + idx0; k < n; k += gstride) {
        float t = targ[k];
        float d = pred[k] - t; float a = fmaf(d, d, PACK);
        int b = min(max((int)(t * 20.0f), 0), NBINS - 1);
        unsafeAtomicAdd(&h[b * TPB + tid], a);
    }

    __syncthreads();

    // ---- epilogue: decode per thread, butterfly per wave, combine per block ----
    const int lane = tid & 63;
    const int wv   = tid >> 6;              // 4 waves
    float my_sse = 0.0f, my_cnt = 0.0f;

    for (int b = 0; b < NBINS; ++b) {
        float A = h[b * TPB + tid];
        float c = floorf(A * (1.0f / 256.0f));   // exact: sse < 256
        float s = A - 256.0f * c;
        #pragma unroll
        for (int m = 32; m; m >>= 1) { c += __shfl_xor(c, m); s += __shfl_xor(s, m); }
        if (lane == b) { my_cnt = c; my_sse = s; }
    }
    __syncthreads();                         // everyone done reading h -> safe to reuse
    if (lane < NBINS) {
        h[wv * 2 * NBINS + lane]         = my_sse;
        h[wv * 2 * NBINS + NBINS + lane] = my_cnt;
    }
    __syncthreads();
    if (tid < NBINS) {
        float ss = 0.0f, cc = 0.0f;
        #pragma unroll
        for (int w = 0; w < TPB / 64; ++w) {
            ss += h[w * 2 * NBINS + tid];
            cc += h[w * 2 * NBINS + NBINS + tid];
        }
        const int set = (int)(blockIdx.x) & setMask;   // 32-way fan-in replication
        unsafeAtomicAdd(&ws[set * 2 * NBINS + tid], ss);
        unsafeAtomicAdd(&ws[set * 2 * NBINS + NBINS + tid], cc);
    }
}

// ---------------- Pass 2: weights + final scalar ----------------
__global__ void dwmse_pass2(const float* __restrict__ ws, float* __restrict__ out,
                            int nsets, float inv_n)
{
    const int t = threadIdx.x;   // 64 threads = 1 wave
    float col = 0.0f;
    if (t < 2 * NBINS) {
        for (int s = 0; s < nsets; ++s) col += ws[s * 2 * NBINS + t];
    }
    // lanes 0..19 hold sse_b; counts live in lanes 20..39
    float sse = col;
    float cnt = __shfl(col, t + 20);

    float w = 0.0f;
    if (t < NBINS) {
        float c = fmaxf(cnt, 1.0f);
        w = __powf(c, -0.9f);
    }
    float s = w;
    #pragma unroll
    for (int off = 32; off > 0; off >>= 1) s += __shfl_down(s, off);
    s = __shfl(s, 0);

    float wb = (s > 0.0f) ? (w * (20.0f / s)) : w;
    wb = fmaxf(wb, 1.0f);

    float contrib = (t < NBINS) ? (wb * sse) : 0.0f;
    #pragma unroll
    for (int off = 32; off > 0; off >>= 1) contrib += __shfl_down(contrib, off);

    if (t == 0) out[0] = contrib * inv_n;
}

extern "C" void kernel_launch(void* const* d_in, const int* in_sizes, int n_in,
                              void* d_out, int out_size, void* d_ws, size_t ws_size,
                              hipStream_t stream)
{
    const float* pred = (const float*)d_in[0];
    const float* targ = (const float*)d_in[1];
    float*       out  = (float*)d_out;
    float*       ws   = (float*)d_ws;
    const int n = in_sizes[0];

    int nsets = NSETS;
    while ((size_t)nsets * 2 * NBINS * sizeof(float) > ws_size && nsets > 1) nsets >>= 1;

    hipMemsetAsync(d_ws, 0, (size_t)nsets * 2 * NBINS * sizeof(float), stream);
    dwmse_pass1<<<BLOCKS, TPB, 0, stream>>>(pred, targ, ws, n, nsets - 1);
    dwmse_pass2<<<1, 64, 0, stream>>>(ws, out, nsets, 1.0f / (float)n);
}

// Round 5
// 200.027 us; speedup vs baseline: 1.3934x; 1.1094x over previous
//
#include <hip/hip_runtime.h>

#define NBINS  20
#define BLOCKS 2048
#define TPB    256
#define PACK   256.0f   // acc[b] = 256*cnt_b + sse_b per thread; cnt<=32, sse<32 -> exact decode

// ---------------- Pass 1: register one-hot histogram (no LDS in hot loop) ----------------
__global__ __launch_bounds__(TPB, 8)
void dwmse_pass1(const float* __restrict__ pred, const float* __restrict__ targ,
                 float* __restrict__ ws, int n, int atomicK)
{
    __shared__ float sp[TPB / 64][2 * NBINS];    // cross-wave combine only (640 B)
    const int tid  = threadIdx.x;
    const int lane = tid & 63;
    const int wv   = tid >> 6;

    float acc[NBINS];
    #pragma unroll
    for (int j = 0; j < NBINS; ++j) acc[j] = 0.0f;

    const int n4 = n >> 2;
    const float4* p4 = reinterpret_cast<const float4*>(pred);
    const float4* t4 = reinterpret_cast<const float4*>(targ);
    const int idx0 = blockIdx.x * TPB + tid;
    const int g    = gridDim.x * TPB;

    for (int i = idx0; i < n4; i += g) {
        float4 p = p4[i];
        float4 t = t4[i];
        float pe[4] = {p.x, p.y, p.z, p.w};
        float te[4] = {t.x, t.y, t.z, t.w};
        #pragma unroll
        for (int e = 0; e < 4; ++e) {
            float d = pe[e] - te[e];
            float a = fmaf(d, d, PACK);
            int b = min(max((int)(te[e] * 20.0f), 0), NBINS - 1);
            #pragma unroll
            for (int j = 0; j < NBINS; ++j)
                acc[j] += (j == b) ? a : 0.0f;    // cmp+cndmask+add: pure VALU, no chain
        }
    }
    // scalar tail (empty for N = 2^24)
    for (int k = (n4 << 2) + idx0; k < n; k += g) {
        float t = targ[k];
        float d = pred[k] - t;
        float a = fmaf(d, d, PACK);
        int b = min(max((int)(t * 20.0f), 0), NBINS - 1);
        #pragma unroll
        for (int j = 0; j < NBINS; ++j)
            acc[j] += (j == b) ? a : 0.0f;
    }

    // ---- epilogue: decode in registers, butterfly per wave, combine waves ----
    float my_sse = 0.0f, my_cnt = 0.0f;
    #pragma unroll
    for (int b = 0; b < NBINS; ++b) {
        float A = acc[b];
        float c = floorf(A * (1.0f / 256.0f));   // exact: sse < 256
        float s = A - 256.0f * c;
        #pragma unroll
        for (int m = 32; m; m >>= 1) { c += __shfl_xor(c, m); s += __shfl_xor(s, m); }
        if (lane == b) { my_cnt = c; my_sse = s; }
    }
    if (lane < NBINS) {
        sp[wv][lane]         = my_sse;
        sp[wv][NBINS + lane] = my_cnt;
    }
    __syncthreads();
    if (tid < 2 * NBINS) {
        float v = 0.0f;
        #pragma unroll
        for (int w = 0; w < TPB / 64; ++w) v += sp[w][tid];
        if (atomicK == 0) {
            ws[tid * gridDim.x + blockIdx.x] = v;          // plain store, no memset needed
        } else {
            unsafeAtomicAdd(&ws[tid * atomicK + ((int)blockIdx.x & (atomicK - 1))], v);
        }
    }
}

// ---------------- Pass 2: reduce K columns per bin-slot, then weights + final ----------------
__global__ void dwmse_pass2(const float* __restrict__ ws, float* __restrict__ out,
                            int K, float inv_n)
{
    __shared__ float s_col[2 * NBINS];
    const int tid  = threadIdx.x;      // 1024 threads = 16 waves
    const int lane = tid & 63;
    const int wv   = tid >> 6;

    for (int j = wv; j < 2 * NBINS; j += 16) {
        float v = 0.0f;
        for (int k = lane; k < K; k += 64) v += ws[j * K + k];
        #pragma unroll
        for (int m = 32; m; m >>= 1) v += __shfl_xor(v, m);
        if (lane == 0) s_col[j] = v;
    }
    __syncthreads();

    if (tid < 64) {
        float col = (tid < 2 * NBINS) ? s_col[tid] : 0.0f;
        float sse = col;
        float cnt = __shfl(col, (tid + 20) & 63);   // lanes 0..19 pick up counts

        float w = 0.0f;
        if (tid < NBINS) w = __powf(fmaxf(cnt, 1.0f), -0.9f);

        float s = w;
        #pragma unroll
        for (int off = 32; off > 0; off >>= 1) s += __shfl_down(s, off);
        s = __shfl(s, 0);

        float wb = (s > 0.0f) ? (w * (20.0f / s)) : w;
        wb = fmaxf(wb, 1.0f);

        float contrib = (tid < NBINS) ? (wb * sse) : 0.0f;
        #pragma unroll
        for (int off = 32; off > 0; off >>= 1) contrib += __shfl_down(contrib, off);

        if (tid == 0) out[0] = contrib * inv_n;
    }
}

extern "C" void kernel_launch(void* const* d_in, const int* in_sizes, int n_in,
                              void* d_out, int out_size, void* d_ws, size_t ws_size,
                              hipStream_t stream)
{
    const float* pred = (const float*)d_in[0];
    const float* targ = (const float*)d_in[1];
    float*       out  = (float*)d_out;
    float*       ws   = (float*)d_ws;
    const int n = in_sizes[0];
    const float inv_n = 1.0f / (float)n;

    const size_t store_bytes = (size_t)(2 * NBINS) * BLOCKS * sizeof(float);
    if (ws_size >= store_bytes) {
        // store path: no memset node, per-block columns, pass2 reduces 2048 cols
        dwmse_pass1<<<BLOCKS, TPB, 0, stream>>>(pred, targ, ws, n, 0);
        dwmse_pass2<<<1, 1024, 0, stream>>>(ws, out, BLOCKS, inv_n);
    } else {
        // fallback: replicated atomic sets
        int K = 32;
        while ((size_t)(2 * NBINS) * K * sizeof(float) > ws_size && K > 1) K >>= 1;
        hipMemsetAsync(d_ws, 0, (size_t)(2 * NBINS) * K * sizeof(float), stream);
        dwmse_pass1<<<BLOCKS, TPB, 0, stream>>>(pred, targ, ws, n, K);
        dwmse_pass2<<<1, 1024, 0, stream>>>(ws, out, K, inv_n);
    }
}

// Round 6
// 183.080 us; speedup vs baseline: 1.5223x; 1.0926x over previous
//
#include <hip/hip_runtime.h>

#define NBINS  20
#define BLOCKS 2048
#define TPB    256
#define TRIPS  8        // 2^24/4 float4s / (2048*256) = 8 exactly
#define PACK   256.0f   // acc[b] = 256*cnt_b + sse_b per thread; cnt<=32, sse<32 -> exact decode

// ---------------- Pass 1: register one-hot histogram, all loads in flight ----------------
__global__ __launch_bounds__(TPB, 4)
void dwmse_pass1(const float* __restrict__ pred, const float* __restrict__ targ,
                 float* __restrict__ ws, int n)
{
    __shared__ float sp[TPB / 64][2 * NBINS];    // cross-wave combine only (640 B)
    const int tid  = threadIdx.x;
    const int lane = tid & 63;
    const int wv   = tid >> 6;

    float acc[NBINS];
    #pragma unroll
    for (int j = 0; j < NBINS; ++j) acc[j] = 0.0f;

    const int n4 = n >> 2;
    const float4* p4 = reinterpret_cast<const float4*>(pred);
    const float4* t4 = reinterpret_cast<const float4*>(targ);
    const int idx0 = blockIdx.x * TPB + tid;
    const int g    = gridDim.x * TPB;

    if (n4 == g * TRIPS) {
        // ---- steady path: issue all 16 dwordx4 loads, then compute ----
        float4 pa[TRIPS], ta[TRIPS];
        #pragma unroll
        for (int u = 0; u < TRIPS; ++u) {
            const int i = idx0 + u * g;
            pa[u] = p4[i];
            ta[u] = t4[i];
        }
        #pragma unroll
        for (int u = 0; u < TRIPS; ++u) {
            float pe[4] = {pa[u].x, pa[u].y, pa[u].z, pa[u].w};
            float te[4] = {ta[u].x, ta[u].y, ta[u].z, ta[u].w};
            #pragma unroll
            for (int e = 0; e < 4; ++e) {
                float d = pe[e] - te[e];
                float a = fmaf(d, d, PACK);
                int b = min(max((int)(te[e] * 20.0f), 0), NBINS - 1);
                #pragma unroll
                for (int j = 0; j < NBINS; ++j)
                    acc[j] += (j == b) ? a : 0.0f;   // cmp+cndmask+add: no dependence chain
            }
        }
    } else {
        // ---- generic fallback ----
        for (int i = idx0; i < n4; i += g) {
            float4 p = p4[i];
            float4 t = t4[i];
            float pe[4] = {p.x, p.y, p.z, p.w};
            float te[4] = {t.x, t.y, t.z, t.w};
            #pragma unroll
            for (int e = 0; e < 4; ++e) {
                float d = pe[e] - te[e];
                float a = fmaf(d, d, PACK);
                int b = min(max((int)(te[e] * 20.0f), 0), NBINS - 1);
                #pragma unroll
                for (int j = 0; j < NBINS; ++j)
                    acc[j] += (j == b) ? a : 0.0f;
            }
        }
        for (int k = (n4 << 2) + idx0; k < n; k += g) {
            float t = targ[k];
            float d = pred[k] - t;
            float a = fmaf(d, d, PACK);
            int b = min(max((int)(t * 20.0f), 0), NBINS - 1);
            #pragma unroll
            for (int j = 0; j < NBINS; ++j)
                acc[j] += (j == b) ? a : 0.0f;
        }
    }

    // ---- epilogue: decode in registers, butterfly per wave, combine waves ----
    float my_sse = 0.0f, my_cnt = 0.0f;
    #pragma unroll
    for (int b = 0; b < NBINS; ++b) {
        float A = acc[b];
        float c = floorf(A * (1.0f / 256.0f));   // exact: sse < 256
        float s = A - 256.0f * c;
        #pragma unroll
        for (int m = 32; m; m >>= 1) { c += __shfl_xor(c, m); s += __shfl_xor(s, m); }
        if (lane == b) { my_cnt = c; my_sse = s; }
    }
    if (lane < NBINS) {
        sp[wv][lane]         = my_sse;
        sp[wv][NBINS + lane] = my_cnt;
    }
    __syncthreads();
    if (tid < 2 * NBINS) {
        float v = 0.0f;
        #pragma unroll
        for (int w = 0; w < TPB / 64; ++w) v += sp[w][tid];
        ws[tid * gridDim.x + blockIdx.x] = v;    // plain store, no atomics, no memset
    }
}

// ---------------- Pass 2: reduce K columns per bin-slot, then weights + final ----------------
__global__ void dwmse_pass2(const float* __restrict__ ws, float* __restrict__ out,
                            int K, float inv_n)
{
    __shared__ float s_col[2 * NBINS];
    const int tid  = threadIdx.x;      // 1024 threads = 16 waves
    const int lane = tid & 63;
    const int wv   = tid >> 6;

    for (int j = wv; j < 2 * NBINS; j += 16) {
        float v = 0.0f;
        for (int k = lane; k < K; k += 64) v += ws[j * K + k];
        #pragma unroll
        for (int m = 32; m; m >>= 1) v += __shfl_xor(v, m);
        if (lane == 0) s_col[j] = v;
    }
    __syncthreads();

    if (tid < 64) {
        float col = (tid < 2 * NBINS) ? s_col[tid] : 0.0f;
        float sse = col;
        float cnt = __shfl(col, (tid + 20) & 63);   // lanes 0..19 pick up counts

        float w = 0.0f;
        if (tid < NBINS) w = __powf(fmaxf(cnt, 1.0f), -0.9f);

        float s = w;
        #pragma unroll
        for (int off = 32; off > 0; off >>= 1) s += __shfl_down(s, off);
        s = __shfl(s, 0);

        float wb = (s > 0.0f) ? (w * (20.0f / s)) : w;
        wb = fmaxf(wb, 1.0f);

        float contrib = (tid < NBINS) ? (wb * sse) : 0.0f;
        #pragma unroll
        for (int off = 32; off > 0; off >>= 1) contrib += __shfl_down(contrib, off);

        if (tid == 0) out[0] = contrib * inv_n;
    }
}

extern "C" void kernel_launch(void* const* d_in, const int* in_sizes, int n_in,
                              void* d_out, int out_size, void* d_ws, size_t ws_size,
                              hipStream_t stream)
{
    const float* pred = (const float*)d_in[0];
    const float* targ = (const float*)d_in[1];
    float*       out  = (float*)d_out;
    float*       ws   = (float*)d_ws;
    const int n = in_sizes[0];
    const float inv_n = 1.0f / (float)n;

    dwmse_pass1<<<BLOCKS, TPB, 0, stream>>>(pred, targ, ws, n);
    dwmse_pass2<<<1, 1024, 0, stream>>>(ws, out, BLOCKS, inv_n);
}